// Round 1
// baseline (219.833 us; speedup 1.0000x reference)
//
#include <hip/hip_runtime.h>

#define VTH 0.5f
#define TAU 0.2f

typedef float v4f __attribute__((ext_vector_type(4)));

#define BLOCK 256
#define VPT 4  // independent 16B loads per thread -> 64 B/thread in flight

// x layout: [64,128,32,32,4] fp32, steps innermost & contiguous.
// One thread = VPT neurons. Each of the VPT loads is wave-contiguous
// (lane i reads base + i*16B within each instruction -> 1 KiB/instr
// coalesced segments), and all VPT loads are independent and issued
// before the dependent LIF compute -> 4x the memory-level parallelism
// of the previous one-load-per-thread version. Pure streaming, zero
// reuse -> nontemporal on both sides to skip L2/L3 allocation (the
// harness's 512 MiB poison fills evict everything between iterations
// anyway). Memory-bound: 256 MiB mandatory traffic, roofline 42.6 us
// at 6.3 TB/s achievable.
__global__ __launch_bounds__(BLOCK) void lif_kernel(
    const v4f* __restrict__ x, v4f* __restrict__ out, int n_vec) {
    int base = blockIdx.x * (BLOCK * VPT) + threadIdx.x;

    if (base + (VPT - 1) * BLOCK < n_vec) {
        // Fast path (always taken for the bench shape: 8,388,608 % 1024 == 0):
        // no guards, all VPT loads batched in flight.
        v4f v[VPT];
        v4f r[VPT];
#pragma unroll
        for (int k = 0; k < VPT; ++k)
            v[k] = __builtin_nontemporal_load(&x[base + k * BLOCK]);
#pragma unroll
        for (int k = 0; k < VPT; ++k) {
            float u, s0, s1, s2, s3;
            u = v[k].x;                          s0 = u > VTH ? 1.0f : 0.0f;
            u = TAU * u * (1.0f - s0) + v[k].y;  s1 = u > VTH ? 1.0f : 0.0f;
            u = TAU * u * (1.0f - s1) + v[k].z;  s2 = u > VTH ? 1.0f : 0.0f;
            u = TAU * u * (1.0f - s2) + v[k].w;  s3 = u > VTH ? 1.0f : 0.0f;
            r[k] = (v4f){s0, s1, s2, s3};
        }
#pragma unroll
        for (int k = 0; k < VPT; ++k)
            __builtin_nontemporal_store(r[k], &out[base + k * BLOCK]);
    } else {
        // Tail path (never taken at the bench shape; kept for correctness
        // on arbitrary sizes).
#pragma unroll
        for (int k = 0; k < VPT; ++k) {
            int i = base + k * BLOCK;
            if (i < n_vec) {
                v4f v = __builtin_nontemporal_load(&x[i]);
                float u, s0, s1, s2, s3;
                u = v.x;                          s0 = u > VTH ? 1.0f : 0.0f;
                u = TAU * u * (1.0f - s0) + v.y;  s1 = u > VTH ? 1.0f : 0.0f;
                u = TAU * u * (1.0f - s1) + v.z;  s2 = u > VTH ? 1.0f : 0.0f;
                u = TAU * u * (1.0f - s2) + v.w;  s3 = u > VTH ? 1.0f : 0.0f;
                v4f r = {s0, s1, s2, s3};
                __builtin_nontemporal_store(r, &out[i]);
            }
        }
    }
}

extern "C" void kernel_launch(void* const* d_in, const int* in_sizes, int n_in,
                              void* d_out, int out_size, void* d_ws, size_t ws_size,
                              hipStream_t stream) {
    const v4f* x = (const v4f*)d_in[0];
    v4f* out = (v4f*)d_out;
    int n_vec = in_sizes[0] / 4;  // 4 steps per neuron, steps contiguous

    int per_block = BLOCK * VPT;
    int grid = (n_vec + per_block - 1) / per_block;
    lif_kernel<<<grid, BLOCK, 0, stream>>>(x, out, n_vec);
}